// Round 3
// baseline (420.553 us; speedup 1.0000x reference)
//
#include <hip/hip_runtime.h>
#include <stdint.h>

// W8A8 int8 GEMM + dequant epilogue, MI355X gfx950.
// R9 = R8 resubmit (container-level failure last round, no counters).
// R8: dbuf counted-vmcnt pipeline *with 2 blocks/CU* (R7 post-mortem: the
// 128 KiB/1-block variant lost the inter-block overlap and regressed).
// BM=256, BN=128, BK=64, 256 thr (4 waves 2Mx2N, per-wave 128x64).
// LDS = 2 x (16K A + 8K B) = 48 KiB -> 2 blocks/CU at ~220 unified regs.
// Prefetch distance 2, s_waitcnt vmcnt(6) steady state, raw s_barrier.
// XOR swizzle for 4-chunk rows: slot cs = cg ^ ((r>>1)&3); 8-lane groups
// cover all 32 banks (<=2 lanes/bank = free, m136).
// out[m,n] = (sum_k A*W + sum_input[m]*zp_w[n]) * si[m]*sw[n] + bias[n]

#define BM 256
#define BN 128
#define BK 64

typedef __attribute__((ext_vector_type(4))) int int32x4;
typedef __attribute__((ext_vector_type(16))) int int32x16;

__device__ __forceinline__ void async_copy16(const uint8_t* g, uint8_t* l) {
  __builtin_amdgcn_global_load_lds(
      (const __attribute__((address_space(1))) uint32_t*)(const void*)g,
      (__attribute__((address_space(3))) uint32_t*)l,
      16, 0, 0);
}

// Coalesced pack, grid-stride: one int32x4 (4 int8-as-int32) -> one uint32.
__global__ __launch_bounds__(256) void pack_kernel(
    const int* __restrict__ A, const int* __restrict__ B,
    uint8_t* __restrict__ A8, uint8_t* __restrict__ B8,
    int nA4, int nTot4) {
  const int stride = gridDim.x * blockDim.x;
  for (int t = blockIdx.x * blockDim.x + threadIdx.x; t < nTot4; t += stride) {
    const int32x4* src;
    uint32_t* dst;
    if (t < nA4) {
      src = (const int32x4*)A + t;
      dst = (uint32_t*)A8 + t;
    } else {
      int u = t - nA4;
      src = (const int32x4*)B + u;
      dst = (uint32_t*)B8 + u;
    }
    int32x4 v = __builtin_nontemporal_load(src);  // read-once stream
    *dst = (uint32_t)(v.x & 255) | ((uint32_t)(v.y & 255) << 8) |
           ((uint32_t)(v.z & 255) << 16) | ((uint32_t)(v.w & 255) << 24);
  }
}

// Stage one 256x64 A tile (4 issues) + 128x64 B tile (2 issues) into one
// LDS buffer. Thread: row_s = tid>>2 (0..63), stored slot cs = tid&3,
// global chunk cg = cs ^ ((tid>>3)&3)  (pre-swizzled global source; LDS
// dest of global_load_lds is linear wave-uniform base + lane*16).
// Invariant: LDS row r (64 B) slot cs holds global chunk cs ^ ((r>>1)&3).
__device__ __forceinline__ void stage_tile(
    const uint8_t* Ab, const uint8_t* Bb, size_t sK, int k0,
    uint8_t* AsBuf, uint8_t* BsBuf, int ldst) {
#pragma unroll
  for (int p = 0; p < 4; ++p)
    async_copy16(Ab + (size_t)(p * 64) * sK + k0, AsBuf + p * 4096 + ldst);
#pragma unroll
  for (int p = 0; p < 2; ++p)
    async_copy16(Bb + (size_t)(p * 64) * sK + k0, BsBuf + p * 4096 + ldst);
}

__global__ __launch_bounds__(256, 2) void w8a8_gemm(
    const uint8_t* __restrict__ A8, const uint8_t* __restrict__ B8,
    const float* __restrict__ bias,
    const float* __restrict__ s_in,
    const float* __restrict__ s_w,
    const float* __restrict__ sum_in,
    const int* __restrict__ zp_w,
    float* __restrict__ out,
    int M, int N, int K) {
  __shared__ uint8_t As[2][BM * BK];  // 2 x 16 KiB
  __shared__ uint8_t Bs[2][BN * BK];  // 2 x  8 KiB  -> 48 KiB total

  const int tid = threadIdx.x;
  // XCD-chunked swizzle (bijective: gridDim.x = 1024, % 8 == 0).
  const int nbn = N / BN;
  int wgs = blockIdx.x;
  if ((gridDim.x & 7) == 0) {
    const int q = gridDim.x >> 3;
    wgs = (blockIdx.x & 7) * q + (blockIdx.x >> 3);
  }
  const int bm = wgs / nbn, bn = wgs % nbn;
  const int row0 = bm * BM, col0 = bn * BN;

  const int wave = tid >> 6, lane = tid & 63;
  const int m32 = lane & 31, half = lane >> 5;
  const int wm = (wave >> 1) * 128;  // 2 wave-rows of 128
  const int wn = (wave & 1) * 64;    // 2 wave-cols of 64
  const size_t sK = (size_t)K;

  // staging geometry (see stage_tile comment)
  const int row_s = tid >> 2;                    // 0..63
  const int cg = (tid & 3) ^ ((tid >> 3) & 3);
  const int ldst = tid * 16;

  const uint8_t* Ab = A8 + (size_t)(row0 + row_s) * sK + cg * 16;
  const uint8_t* Bb = B8 + (size_t)(col0 + row_s) * sK + cg * 16;

  int32x16 acc[4][2] = {};

  const int NT = K / BK;
  // Prologue: fill both buffers (12 loads/thread in flight).
  stage_tile(Ab, Bb, sK, 0, &As[0][0], &Bs[0][0], ldst);
  stage_tile(Ab, Bb, sK, BK, &As[1][0], &Bs[1][0], ldst);

  int cur = 0;
  const int swzr = (m32 >> 1) & 3;
  for (int kt = 0; kt < NT; ++kt) {
    // Tile kt's 6 loads complete; tile kt+1's 6 may stay in flight.
    if (kt + 1 < NT) {
      asm volatile("s_waitcnt vmcnt(6)" ::: "memory");
    } else {
      asm volatile("s_waitcnt vmcnt(0)" ::: "memory");
    }
    __builtin_amdgcn_s_barrier();

    const uint8_t* Ac = &As[cur][0];
    const uint8_t* Bc = &Bs[cur][0];
    __builtin_amdgcn_s_setprio(1);
#pragma unroll
    for (int ks = 0; ks < 2; ++ks) {
      const int gran = ((ks * 2 + half) ^ swzr) * 16;
      int32x4 afrag[4], bfrag[2];
#pragma unroll
      for (int i = 0; i < 4; ++i)
        afrag[i] = *(const int32x4*)&Ac[(wm + i * 32 + m32) * BK + gran];
#pragma unroll
      for (int j = 0; j < 2; ++j)
        bfrag[j] = *(const int32x4*)&Bc[(wn + j * 32 + m32) * BK + gran];
#pragma unroll
      for (int i = 0; i < 4; ++i)
#pragma unroll
        for (int j = 0; j < 2; ++j)
          acc[i][j] = __builtin_amdgcn_mfma_i32_32x32x32_i8(
              afrag[i], bfrag[j], acc[i][j], 0, 0, 0);
    }
    __builtin_amdgcn_s_setprio(0);
    // All our ds_reads of buf[cur] retired before anyone overwrites it.
    asm volatile("s_waitcnt lgkmcnt(0)" ::: "memory");
    __builtin_amdgcn_s_barrier();
    if (kt + 2 < NT)
      stage_tile(Ab, Bb, sK, (kt + 2) * BK, &As[cur][0], &Bs[cur][0], ldst);
    cur ^= 1;
  }

  // Epilogue: 32x32 C/D layout col=lane&31, row=(reg&3)+8*(reg>>2)+4*(lane>>5).
  float swj[2], zpj[2], bj[2];
#pragma unroll
  for (int j = 0; j < 2; ++j) {
    int gc = col0 + wn + j * 32 + m32;
    swj[j] = s_w[gc];
    zpj[j] = (float)zp_w[gc];
    bj[j] = bias[gc];
  }
#pragma unroll
  for (int i = 0; i < 4; ++i) {
#pragma unroll
    for (int reg = 0; reg < 16; ++reg) {
      int gr = row0 + wm + i * 32 + (reg & 3) + 8 * (reg >> 2) + 4 * half;
      float siv = s_in[gr];
      float suv = sum_in[gr];
      float* orow = out + (size_t)gr * N + col0 + wn + m32;
#pragma unroll
      for (int j = 0; j < 2; ++j) {
        float v = ((float)acc[i][j][reg] + suv * zpj[j]) * (siv * swj[j]) + bj[j];
        __builtin_nontemporal_store(v, &orow[j * 32]);
      }
    }
  }
}

// Fallback (ws too small): unpacked int32 inputs, BK=64, VALU pack + ds_write.
__global__ __launch_bounds__(256) void w8a8_gemm_fallback(
    const int* __restrict__ A32, const int* __restrict__ B32,
    const float* __restrict__ bias,
    const float* __restrict__ s_in,
    const float* __restrict__ s_w,
    const float* __restrict__ sum_in,
    const int* __restrict__ zp_w,
    float* __restrict__ out,
    int M, int N, int K) {
  __shared__ uint8_t As[128 * 64];
  __shared__ uint8_t Bs[128 * 64];
  const int tid = threadIdx.x;
  const int bm = blockIdx.y, bn = blockIdx.x;
  const int row0 = bm * 128, col0 = bn * 128;
  const int wave = tid >> 6, lane = tid & 63;
  const int quad = lane >> 4, r = lane & 15;
  const int wm = (wave >> 1) * 64, wn = (wave & 1) * 64;
  const int lin = tid * 16;
  const int srow = lin >> 6;
  const int scol = lin & 63;
  const size_t sK = (size_t)K;
  int32x4 acc[4][4] = {};
  for (int k0 = 0; k0 < K; k0 += 64) {
#pragma unroll
    for (int c = 0; c < 2; ++c) {
      const int* ag = A32 + (size_t)(row0 + srow + c * 64) * sK + k0 + scol;
      const int* bg = B32 + (size_t)(col0 + srow + c * 64) * sK + k0 + scol;
      int32x4 pa, pb;
#pragma unroll
      for (int q = 0; q < 4; ++q) {
        int4 va = ((const int4*)ag)[q];
        int4 vb = ((const int4*)bg)[q];
        pa[q] = (int)((uint32_t)(va.x & 255) | ((uint32_t)(va.y & 255) << 8) |
                      ((uint32_t)(va.z & 255) << 16) | ((uint32_t)(va.w & 255) << 24));
        pb[q] = (int)((uint32_t)(vb.x & 255) | ((uint32_t)(vb.y & 255) << 8) |
                      ((uint32_t)(vb.z & 255) << 16) | ((uint32_t)(vb.w & 255) << 24));
      }
      *(int32x4*)&As[lin + c * 4096] = pa;
      *(int32x4*)&Bs[lin + c * 4096] = pb;
    }
    __syncthreads();
    int32x4 afrag[4], bfrag[4];
#pragma unroll
    for (int i = 0; i < 4; ++i)
      afrag[i] = *(const int32x4*)&As[(wm + i * 16 + r) * 64 + quad * 16];
#pragma unroll
    for (int j = 0; j < 4; ++j)
      bfrag[j] = *(const int32x4*)&Bs[(wn + j * 16 + r) * 64 + quad * 16];
#pragma unroll
    for (int i = 0; i < 4; ++i)
#pragma unroll
      for (int j = 0; j < 4; ++j)
        acc[i][j] = __builtin_amdgcn_mfma_i32_16x16x64_i8(afrag[i], bfrag[j],
                                                          acc[i][j], 0, 0, 0);
    __syncthreads();
  }
  float swj[4], zpj[4], bj[4];
#pragma unroll
  for (int j = 0; j < 4; ++j) {
    int gc = col0 + wn + j * 16 + r;
    swj[j] = s_w[gc];
    zpj[j] = (float)zp_w[gc];
    bj[j] = bias[gc];
  }
#pragma unroll
  for (int i = 0; i < 4; ++i) {
#pragma unroll
    for (int t = 0; t < 4; ++t) {
      int gr = row0 + wm + i * 16 + quad * 4 + t;
      float siv = s_in[gr];
      float suv = sum_in[gr];
      float* orow = out + (size_t)gr * N + col0 + wn + r;
#pragma unroll
      for (int j = 0; j < 4; ++j) {
        float v = ((float)acc[i][j][t] + suv * zpj[j]) * (siv * swj[j]) + bj[j];
        orow[j * 16] = v;
      }
    }
  }
}

extern "C" void kernel_launch(void* const* d_in, const int* in_sizes, int n_in,
                              void* d_out, int out_size, void* d_ws, size_t ws_size,
                              hipStream_t stream) {
  const int* x_q = (const int*)d_in[0];
  const int* w_q = (const int*)d_in[1];
  const float* bias = (const float*)d_in[2];
  const float* s_in = (const float*)d_in[3];
  const float* s_w = (const float*)d_in[4];
  const float* sum_in = (const float*)d_in[5];
  const int* zp_w = (const int*)d_in[6];
  float* out = (float*)d_out;

  const int M = in_sizes[3];
  const int N = in_sizes[2];
  const int K = in_sizes[0] / M;

  const size_t needA = (size_t)M * K;
  const size_t needB = (size_t)N * K;

  if (ws_size >= needA + needB && (M % BM) == 0 && (N % BN) == 0 &&
      (K % BK) == 0 && (K / BK) >= 2) {
    uint8_t* A8 = (uint8_t*)d_ws;
    uint8_t* B8 = A8 + needA;
    const int nA4 = (int)(needA / 4);
    const int nTot4 = (int)((needA + needB) / 4);
    int nblk = (nTot4 + 255) / 256;
    if (nblk > 2048) nblk = 2048;
    pack_kernel<<<nblk, 256, 0, stream>>>(x_q, w_q, A8, B8, nA4, nTot4);
    dim3 grid((M / BM) * (N / BN)), block(256);
    w8a8_gemm<<<grid, block, 0, stream>>>(A8, B8, bias, s_in, s_w, sum_in,
                                          zp_w, out, M, N, K);
  } else {
    dim3 grid(N / 128, M / 128), block(256);
    w8a8_gemm_fallback<<<grid, block, 0, stream>>>(x_q, w_q, bias, s_in, s_w,
                                                   sum_in, zp_w, out, M, N, K);
  }
}

// Round 4
// 392.544 us; speedup vs baseline: 1.0714x; 1.0714x over previous
//
#include <hip/hip_runtime.h>
#include <stdint.h>

// W8A8 int8 GEMM + dequant epilogue, MI355X gfx950.
// R10: m201-style phase-split pipeline. BM=BN=256, BK=128, 512 thr
// (8 waves 2Mx4N, wave tile 128x64, acc 4x2 of 32x32, ratio 0.75).
// LDS = 2 x (32K A + 32K B) = 128 KiB -> 1 block/CU, 2 waves/SIMD.
// Per K-tile: 4 phases {6 ds_read, 2 stage-issues(kt+1), barrier,
// lgkmcnt(0), setprio1, 8 MFMA, setprio0, barrier}; vmcnt(0) once per
// tile, aged a full tile (~2300cyc >> L2 latency) so it's a no-wait drain.
// BK=128 8-chunk XOR swizzle (measured conflict-free R3/R5/R6/R7;
// the BK=64 4-chunk variant measured 1.26e7 conflicts in R9 - never again).
// out[m,n] = (sum_k A*W + sum_input[m]*zp_w[n]) * si[m]*sw[n] + bias[n]

#define BM 256
#define BN 256
#define BK 128

typedef __attribute__((ext_vector_type(4))) int int32x4;
typedef __attribute__((ext_vector_type(16))) int int32x16;

__device__ __forceinline__ void async_copy16(const uint8_t* g, uint8_t* l) {
  __builtin_amdgcn_global_load_lds(
      (const __attribute__((address_space(1))) uint32_t*)(const void*)g,
      (__attribute__((address_space(3))) uint32_t*)l,
      16, 0, 0);
}

// Coalesced pack, grid-stride: one int32x4 (4 int8-as-int32) -> one uint32.
__global__ __launch_bounds__(256) void pack_kernel(
    const int* __restrict__ A, const int* __restrict__ B,
    uint8_t* __restrict__ A8, uint8_t* __restrict__ B8,
    int nA4, int nTot4) {
  const int stride = gridDim.x * blockDim.x;
  for (int t = blockIdx.x * blockDim.x + threadIdx.x; t < nTot4; t += stride) {
    const int32x4* src;
    uint32_t* dst;
    if (t < nA4) {
      src = (const int32x4*)A + t;
      dst = (uint32_t*)A8 + t;
    } else {
      int u = t - nA4;
      src = (const int32x4*)B + u;
      dst = (uint32_t*)B8 + u;
    }
    int32x4 v = __builtin_nontemporal_load(src);  // read-once stream
    *dst = (uint32_t)(v.x & 255) | ((uint32_t)(v.y & 255) << 8) |
           ((uint32_t)(v.z & 255) << 16) | ((uint32_t)(v.w & 255) << 24);
  }
}

__global__ __launch_bounds__(512, 2) void w8a8_gemm(
    const uint8_t* __restrict__ A8, const uint8_t* __restrict__ B8,
    const float* __restrict__ bias,
    const float* __restrict__ s_in,
    const float* __restrict__ s_w,
    const float* __restrict__ sum_in,
    const int* __restrict__ zp_w,
    float* __restrict__ out,
    int M, int N, int K) {
  __shared__ uint8_t As[2][BM * BK];  // 2 x 32 KiB
  __shared__ uint8_t Bs[2][BN * BK];  // 2 x 32 KiB  -> 128 KiB total

  const int tid = threadIdx.x;
  const int bm = blockIdx.y, bn = blockIdx.x;  // plain 2D grid (best FETCH, R6)
  const int row0 = bm * BM, col0 = bn * BN;

  const int wave = tid >> 6, lane = tid & 63;
  const int m32 = lane & 31, half = lane >> 5;
  const int wm = (wave >> 2) * 128;  // 2 wave-rows of 128
  const int wn = (wave & 3) * 64;    // 4 wave-cols of 64
  const size_t sK = (size_t)K;

  // Staging (512 threads): row_s = tid>>3 (0..63), slot cs = tid&7,
  // global chunk cg = cs ^ ((tid>>4)&7). LDS row r slot cs holds global
  // chunk cs ^ ((r>>1)&7); issue p covers rows [p*64, p*64+64).
  const int row_s = tid >> 3;
  const int cg = (tid & 7) ^ ((tid >> 4) & 7);
  const int ldst = tid * 16;

  const uint8_t* Ab = A8 + (size_t)(row0 + row_s) * sK + cg * 16;
  const uint8_t* Bb = B8 + (size_t)(col0 + row_s) * sK + cg * 16;

  int32x16 acc[4][2] = {};

  const int NT = K / BK;
  // Prologue: stage tile 0 into buf 0 (8 issues).
#pragma unroll
  for (int p = 0; p < 4; ++p)
    async_copy16(Ab + (size_t)(p * 64) * sK, &As[0][p * 8192 + ldst]);
#pragma unroll
  for (int p = 0; p < 4; ++p)
    async_copy16(Bb + (size_t)(p * 64) * sK, &Bs[0][p * 8192 + ldst]);

  int cur = 0;
  const int swzr = (m32 >> 1) & 7;
  for (int kt = 0; kt < NT; ++kt) {
    // buf[cur]'s stages (issued >= 1 full tile ago) must have landed.
    asm volatile("s_waitcnt vmcnt(0)" ::: "memory");
    __builtin_amdgcn_s_barrier();

    const uint8_t* Ac = &As[cur][0];
    const uint8_t* Bc = &Bs[cur][0];
    uint8_t* Anx = &As[cur ^ 1][0];
    uint8_t* Bnx = &Bs[cur ^ 1][0];
    const int knx = (kt + 1) * BK;
    const bool more = (kt + 1 < NT);

#pragma unroll
    for (int ks = 0; ks < 4; ++ks) {
      // --- phase ks: ds-reads for this ks ---
      const int gran = ((ks * 2 + half) ^ swzr) * 16;
      int32x4 afrag[4], bfrag[2];
#pragma unroll
      for (int i = 0; i < 4; ++i)
        afrag[i] = *(const int32x4*)&Ac[(wm + i * 32 + m32) * BK + gran];
#pragma unroll
      for (int j = 0; j < 2; ++j)
        bfrag[j] = *(const int32x4*)&Bc[(wn + j * 32 + m32) * BK + gran];
      // --- 2 stage-issues of tile kt+1 (A in phases 0-1, B in 2-3) ---
      if (more) {
        if (ks < 2) {
#pragma unroll
          for (int p = 0; p < 2; ++p) {
            const int pa = ks * 2 + p;
            async_copy16(Ab + (size_t)(pa * 64) * sK + knx,
                         Anx + pa * 8192 + ldst);
          }
        } else {
#pragma unroll
          for (int p = 0; p < 2; ++p) {
            const int pb = (ks - 2) * 2 + p;
            async_copy16(Bb + (size_t)(pb * 64) * sK + knx,
                         Bnx + pb * 8192 + ldst);
          }
        }
      }
      // --- barrier; wait reads; MFMA cluster ---
      __builtin_amdgcn_s_barrier();
      asm volatile("s_waitcnt lgkmcnt(0)" ::: "memory");
      __builtin_amdgcn_s_setprio(1);
#pragma unroll
      for (int i = 0; i < 4; ++i)
#pragma unroll
        for (int j = 0; j < 2; ++j)
          acc[i][j] = __builtin_amdgcn_mfma_i32_32x32x32_i8(
              afrag[i], bfrag[j], acc[i][j], 0, 0, 0);
      __builtin_amdgcn_s_setprio(0);
      if (ks < 3) __builtin_amdgcn_s_barrier();
    }
    cur ^= 1;
  }

  // Epilogue: 32x32 C/D layout col=lane&31, row=(reg&3)+8*(reg>>2)+4*(lane>>5).
  float swj[2], zpj[2], bj[2];
#pragma unroll
  for (int j = 0; j < 2; ++j) {
    int gc = col0 + wn + j * 32 + m32;
    swj[j] = s_w[gc];
    zpj[j] = (float)zp_w[gc];
    bj[j] = bias[gc];
  }
#pragma unroll
  for (int i = 0; i < 4; ++i) {
#pragma unroll
    for (int reg = 0; reg < 16; ++reg) {
      int gr = row0 + wm + i * 32 + (reg & 3) + 8 * (reg >> 2) + 4 * half;
      float siv = s_in[gr];
      float suv = sum_in[gr];
      float* orow = out + (size_t)gr * N + col0 + wn + m32;
#pragma unroll
      for (int j = 0; j < 2; ++j) {
        float v = ((float)acc[i][j][reg] + suv * zpj[j]) * (siv * swj[j]) + bj[j];
        __builtin_nontemporal_store(v, &orow[j * 32]);
      }
    }
  }
}

// Fallback (ws too small): unpacked int32 inputs, BK=64, VALU pack + ds_write.
__global__ __launch_bounds__(256) void w8a8_gemm_fallback(
    const int* __restrict__ A32, const int* __restrict__ B32,
    const float* __restrict__ bias,
    const float* __restrict__ s_in,
    const float* __restrict__ s_w,
    const float* __restrict__ sum_in,
    const int* __restrict__ zp_w,
    float* __restrict__ out,
    int M, int N, int K) {
  __shared__ uint8_t As[128 * 64];
  __shared__ uint8_t Bs[128 * 64];
  const int tid = threadIdx.x;
  const int bm = blockIdx.y, bn = blockIdx.x;
  const int row0 = bm * 128, col0 = bn * 128;
  const int wave = tid >> 6, lane = tid & 63;
  const int quad = lane >> 4, r = lane & 15;
  const int wm = (wave >> 1) * 64, wn = (wave & 1) * 64;
  const int lin = tid * 16;
  const int srow = lin >> 6;
  const int scol = lin & 63;
  const size_t sK = (size_t)K;
  int32x4 acc[4][4] = {};
  for (int k0 = 0; k0 < K; k0 += 64) {
#pragma unroll
    for (int c = 0; c < 2; ++c) {
      const int* ag = A32 + (size_t)(row0 + srow + c * 64) * sK + k0 + scol;
      const int* bg = B32 + (size_t)(col0 + srow + c * 64) * sK + k0 + scol;
      int32x4 pa, pb;
#pragma unroll
      for (int q = 0; q < 4; ++q) {
        int4 va = ((const int4*)ag)[q];
        int4 vb = ((const int4*)bg)[q];
        pa[q] = (int)((uint32_t)(va.x & 255) | ((uint32_t)(va.y & 255) << 8) |
                      ((uint32_t)(va.z & 255) << 16) | ((uint32_t)(va.w & 255) << 24));
        pb[q] = (int)((uint32_t)(vb.x & 255) | ((uint32_t)(vb.y & 255) << 8) |
                      ((uint32_t)(vb.z & 255) << 16) | ((uint32_t)(vb.w & 255) << 24));
      }
      *(int32x4*)&As[lin + c * 4096] = pa;
      *(int32x4*)&Bs[lin + c * 4096] = pb;
    }
    __syncthreads();
    int32x4 afrag[4], bfrag[4];
#pragma unroll
    for (int i = 0; i < 4; ++i)
      afrag[i] = *(const int32x4*)&As[(wm + i * 16 + r) * 64 + quad * 16];
#pragma unroll
    for (int j = 0; j < 4; ++j)
      bfrag[j] = *(const int32x4*)&Bs[(wn + j * 16 + r) * 64 + quad * 16];
#pragma unroll
    for (int i = 0; i < 4; ++i)
#pragma unroll
      for (int j = 0; j < 4; ++j)
        acc[i][j] = __builtin_amdgcn_mfma_i32_16x16x64_i8(afrag[i], bfrag[j],
                                                          acc[i][j], 0, 0, 0);
    __syncthreads();
  }
  float swj[4], zpj[4], bj[4];
#pragma unroll
  for (int j = 0; j < 4; ++j) {
    int gc = col0 + wn + j * 16 + r;
    swj[j] = s_w[gc];
    zpj[j] = (float)zp_w[gc];
    bj[j] = bias[gc];
  }
#pragma unroll
  for (int i = 0; i < 4; ++i) {
#pragma unroll
    for (int t = 0; t < 4; ++t) {
      int gr = row0 + wm + i * 16 + quad * 4 + t;
      float siv = s_in[gr];
      float suv = sum_in[gr];
      float* orow = out + (size_t)gr * N + col0 + wn + r;
#pragma unroll
      for (int j = 0; j < 4; ++j) {
        float v = ((float)acc[i][j][t] + suv * zpj[j]) * (siv * swj[j]) + bj[j];
        orow[j * 16] = v;
      }
    }
  }
}

extern "C" void kernel_launch(void* const* d_in, const int* in_sizes, int n_in,
                              void* d_out, int out_size, void* d_ws, size_t ws_size,
                              hipStream_t stream) {
  const int* x_q = (const int*)d_in[0];
  const int* w_q = (const int*)d_in[1];
  const float* bias = (const float*)d_in[2];
  const float* s_in = (const float*)d_in[3];
  const float* s_w = (const float*)d_in[4];
  const float* sum_in = (const float*)d_in[5];
  const int* zp_w = (const int*)d_in[6];
  float* out = (float*)d_out;

  const int M = in_sizes[3];
  const int N = in_sizes[2];
  const int K = in_sizes[0] / M;

  const size_t needA = (size_t)M * K;
  const size_t needB = (size_t)N * K;

  if (ws_size >= needA + needB && (M % BM) == 0 && (N % BN) == 0 &&
      (K % BK) == 0 && (K / BK) >= 2) {
    uint8_t* A8 = (uint8_t*)d_ws;
    uint8_t* B8 = A8 + needA;
    const int nA4 = (int)(needA / 4);
    const int nTot4 = (int)((needA + needB) / 4);
    int nblk = (nTot4 + 255) / 256;
    if (nblk > 2048) nblk = 2048;
    pack_kernel<<<nblk, 256, 0, stream>>>(x_q, w_q, A8, B8, nA4, nTot4);
    dim3 grid(N / BN, M / BM), block(512);
    w8a8_gemm<<<grid, block, 0, stream>>>(A8, B8, bias, s_in, s_w, sum_in,
                                          zp_w, out, M, N, K);
  } else {
    dim3 grid(N / 128, M / 128), block(256);
    w8a8_gemm_fallback<<<grid, block, 0, stream>>>(x_q, w_q, bias, s_in, s_w,
                                                   sum_in, zp_w, out, M, N, K);
  }
}